// Round 14
// baseline (23.398 us; speedup 1.0000x reference)
//
#include <hip/hip_runtime.h>
#include <hip/hip_bf16.h>

typedef __attribute__((ext_vector_type(8))) short bf16x8;
typedef __attribute__((ext_vector_type(4))) float f32x4;

#define T_DIM 4096
#define B_DIM 16
#define D_DIM 128
#define TILE 128         // q rows per tile
#define NTILE 2          // tiles per block (pipelined)
#define ROWS 160         // staged rows per tile: t0-16 .. t0+143
#define SROW 136         // bf16 units per row (272 B, 16B-aligned)
#define NEGV -1e30f
#define NBLK 256         // 1 block/CU, fully resident
#define SCALE (1.0f / 131072.0f)   // 1 / (B * 2T)

// Barrier that does NOT drain vmcnt (LDS visibility only): prefetch global
// loads stay in flight across it.
#define LDS_BARRIER() asm volatile("s_waitcnt lgkmcnt(0)\n\ts_barrier" ::: "memory")

__global__ __launch_bounds__(1024) void lcl_main(
    const float* __restrict__ mot, const float* __restrict__ aud,
    float* __restrict__ ws)
{
    __shared__ unsigned short sm[ROWS * SROW];
    __shared__ unsigned short sa[ROWS * SROW];
    __shared__ float invM[ROWS], invA[ROWS];   // inv row norms (of bf16 rows)
    __shared__ float redL[16], redC[16];

    const int tid  = threadIdx.x;
    const int lane = tid & 63;
    const int wv   = tid >> 6;     // 0..15
    const int g32  = tid >> 5;     // 0..31 staging group
    const int l32  = tid & 31;

    // XCD-aware bijective swizzle (256 % 8 == 0): same-XCD blocks are
    // t-adjacent within the same batch -> halo rows hit the same L2.
    const int lin = blockIdx.x;                       // 0..255
    const int swz = (lin & 7) * (NBLK / 8) + (lin >> 3);
    const int by  = swz >> 4;                         // batch 0..15
    const int tg  = swz & 15;                         // t-group (256 t's)
    const int tbase = tg * (NTILE * TILE);
    const size_t base = (size_t)by * (T_DIM * D_DIM);

    // per-wave task: dir = wv>>3, mi = wv&7
    const int dir = wv >> 3;
    const int mi  = wv & 7;
    const unsigned short* q = dir ? sa : sm;
    const unsigned short* k = dir ? sm : sa;
    float* invKarr = dir ? invM : invA;        // this wave's k-tensor norms
    const float* invQarr = dir ? invA : invM;

    const int fr    = lane & 15;
    const int fch   = (lane >> 4) * 8;
    const int col16 = lane & 15;
    const int g     = lane >> 4;

    // ---- prologue: issue tile-0 loads (held in registers) ----
    float4 vm[5], va[5];
    {
        const size_t off = base + (size_t)(tbase - 16 + g32) * D_DIM + l32 * 4;
        const float* spm = mot + off;
        const float* spa = aud + off;
        #pragma unroll
        for (int i = 0; i < 5; ++i) {
            const bool ok = (unsigned)(tbase - 16 + g32 + 32 * i) < (unsigned)T_DIM;
            vm[i] = make_float4(0.f, 0.f, 0.f, 0.f);
            va[i] = vm[i];
            if (ok) {
                vm[i] = *reinterpret_cast<const float4*>(spm + (size_t)(32 * i) * D_DIM);
                va[i] = *reinterpret_cast<const float4*>(spa + (size_t)(32 * i) * D_DIM);
            }
        }
    }

    float lossW = 0.f, corrW = 0.f;

    #pragma unroll
    for (int tile = 0; tile < NTILE; ++tile) {
        const int t0 = tbase + tile * TILE;

        // ---- convert held registers -> bf16 -> LDS ----
        {
            unsigned short* dpm = sm + g32 * SROW + l32 * 4;
            unsigned short* dpa = sa + g32 * SROW + l32 * 4;
            #pragma unroll
            for (int i = 0; i < 5; ++i) {
                union { __hip_bfloat16 h[4]; uint2 u; } pm, pa;
                pm.h[0] = __float2bfloat16(vm[i].x);
                pm.h[1] = __float2bfloat16(vm[i].y);
                pm.h[2] = __float2bfloat16(vm[i].z);
                pm.h[3] = __float2bfloat16(vm[i].w);
                pa.h[0] = __float2bfloat16(va[i].x);
                pa.h[1] = __float2bfloat16(va[i].y);
                pa.h[2] = __float2bfloat16(va[i].z);
                pa.h[3] = __float2bfloat16(va[i].w);
                *reinterpret_cast<uint2*>(dpm + 32 * i * SROW) = pm.u;
                *reinterpret_cast<uint2*>(dpa + 32 * i * SROW) = pa.u;
            }
        }

        // ---- issue NEXT tile's loads; stay in flight across barriers ----
        if (tile + 1 < NTILE) {
            const int tn = t0 + TILE;
            const size_t off = base + (size_t)(tn - 16 + g32) * D_DIM + l32 * 4;
            const float* spm = mot + off;
            const float* spa = aud + off;
            #pragma unroll
            for (int i = 0; i < 5; ++i) {
                const bool ok = (unsigned)(tn - 16 + g32 + 32 * i) < (unsigned)T_DIM;
                vm[i] = make_float4(0.f, 0.f, 0.f, 0.f);
                va[i] = vm[i];
                if (ok) {
                    vm[i] = *reinterpret_cast<const float4*>(spm + (size_t)(32 * i) * D_DIM);
                    va[i] = *reinterpret_cast<const float4*>(spa + (size_t)(32 * i) * D_DIM);
                }
            }
        }
        LDS_BARRIER();     // barrier A: staging visible (vmcnt NOT drained)

        // ---- SWAPPED MFMA: A = k rows, B = q rows -> C[row=k_jj][col=q_t]
        // Norm self-Grams reuse already-loaded A fragments (0 extra ds_reads).
        // Coverage: n0 -> k-block mi (0..7); n1 (mi>=6) -> k-blocks 8,9.
        f32x4 acc0 = {0.f,0.f,0.f,0.f}, acc1 = acc0, acc2 = acc0;
        f32x4 n0 = acc0, n1 = acc0;
        const unsigned short* qrow = q + (16 * (mi + 1) + fr) * SROW + fch;
        const unsigned short* k0   = k + ((mi + 0) * 16 + fr) * SROW + fch;
        const unsigned short* k1   = k + ((mi + 1) * 16 + fr) * SROW + fch;
        const unsigned short* k2   = k + ((mi + 2) * 16 + fr) * SROW + fch;
        #pragma unroll
        for (int ks = 0; ks < 4; ++ks) {
            bf16x8 bq = *reinterpret_cast<const bf16x8*>(qrow + ks * 32);
            bf16x8 a0 = *reinterpret_cast<const bf16x8*>(k0   + ks * 32);
            bf16x8 a1 = *reinterpret_cast<const bf16x8*>(k1   + ks * 32);
            bf16x8 a2 = *reinterpret_cast<const bf16x8*>(k2   + ks * 32);
            acc0 = __builtin_amdgcn_mfma_f32_16x16x32_bf16(a0, bq, acc0, 0, 0, 0);
            acc1 = __builtin_amdgcn_mfma_f32_16x16x32_bf16(a1, bq, acc1, 0, 0, 0);
            acc2 = __builtin_amdgcn_mfma_f32_16x16x32_bf16(a2, bq, acc2, 0, 0, 0);
            n0   = __builtin_amdgcn_mfma_f32_16x16x32_bf16(a0, a0, n0, 0, 0, 0);
            if (mi >= 6)
                n1 = __builtin_amdgcn_mfma_f32_16x16x32_bf16(a2, a2, n1, 0, 0, 0);
        }

        // ---- Gram diagonals -> inv norms (k-blocks 0..9, both tensors) ----
        if ((col16 >> 2) == g) {
            const int r = col16 & 3;
            invKarr[16 * mi + col16] = 1.0f / fmaxf(sqrtf(n0[r]), 1e-12f);
            if (mi >= 6)
                invKarr[16 * (mi + 2) + col16] = 1.0f / fmaxf(sqrtf(n1[r]), 1e-12f);
        }
        LDS_BARRIER();     // barrier B: norms visible (vmcnt NOT drained)

        // ---- band reduction: lane owns q-row t=t0+16*mi+col16 ----
        // Single shared max serves both LSEs; loss = log(s/sp).
        const float scq10 = 10.0f * invQarr[16 * (mi + 1) + col16];
        const f32x4 sck0 = *reinterpret_cast<const f32x4*>(&invKarr[16 * (mi + 0) + 4 * g]);
        const f32x4 sck1 = *reinterpret_cast<const f32x4*>(&invKarr[16 * (mi + 1) + 4 * g]);
        const f32x4 sck2 = *reinterpret_cast<const f32x4*>(&invKarr[16 * (mi + 2) + 4 * g]);

        const int jbase  = t0 - 16 + 16 * mi + 4 * g;   // + 16b + r = key idx
        const int kkbase = 4 * g - col16;               // + 16b + r = kk

        float lv[12];
        bool  pmk[12];
        float mx = NEGV, mxp = NEGV;
        #pragma unroll
        for (int bb = 0; bb < 3; ++bb) {
            const f32x4 acc = (bb == 0) ? acc0 : ((bb == 1) ? acc1 : acc2);
            const f32x4 sck = (bb == 0) ? sck0 : ((bb == 1) ? sck1 : sck2);
            #pragma unroll
            for (int r = 0; r < 4; ++r) {
                const int kk = kkbase + 16 * bb + r;
                const int jg = jbase  + 16 * bb + r;
                const bool ok = ((unsigned)kk < 32u) && ((unsigned)jg < (unsigned)T_DIM);
                const float li = ok ? acc[r] * (scq10 * sck[r]) : NEGV;
                const bool  pi = ((unsigned)(kk - 12) < 8u);
                lv[bb * 4 + r]  = li;
                pmk[bb * 4 + r] = pi;
                mx  = fmaxf(mx, li);
                mxp = pi ? fmaxf(mxp, li) : mxp;
            }
        }
        mx  = fmaxf(mx,  __shfl_xor(mx,  16));
        mx  = fmaxf(mx,  __shfl_xor(mx,  32));
        mxp = fmaxf(mxp, __shfl_xor(mxp, 16));
        mxp = fmaxf(mxp, __shfl_xor(mxp, 32));

        float s = 0.f, sp = 0.f;
        #pragma unroll
        for (int i = 0; i < 12; ++i) {
            const float e = __expf(lv[i] - mx);   // NEGV entries -> 0
            s  += e;
            sp += pmk[i] ? e : 0.f;
        }
        s  += __shfl_xor(s,  16);  s  += __shfl_xor(s,  32);
        sp += __shfl_xor(sp, 16);  sp += __shfl_xor(sp, 32);

        if (g == 0) {                    // lanes 0..15: one q-row each
            lossW += __logf(s / sp);
            corrW += (mxp >= mx) ? 1.0f : 0.0f;
        }
        // no end-of-tile barrier: next converts write sm/sa whose readers
        // (this tile's MFMA ds_reads) completed before barrier B; band
        // reduce reads only invM/invA, next overwritten after next barrier A.
    }

    // ---- block reduction -> per-block partials in ws (no atomics) ----
    #pragma unroll
    for (int m = 32; m; m >>= 1) {
        lossW += __shfl_xor(lossW, m);
        corrW += __shfl_xor(corrW, m);
    }
    if (lane == 0) { redL[wv] = lossW; redC[wv] = corrW; }
    __syncthreads();
    if (tid == 0) {
        float L = 0.f, C = 0.f;
        #pragma unroll
        for (int i = 0; i < 16; ++i) { L += redL[i]; C += redC[i]; }
        ws[2 * swz]     = L;
        ws[2 * swz + 1] = C;
    }
}

__global__ __launch_bounds__(256) void lcl_final(
    const float* __restrict__ ws, float* __restrict__ out)
{
    const int tid = threadIdx.x;
    const float2 v = reinterpret_cast<const float2*>(ws)[tid];   // 256 partials
    float L = v.x, C = v.y;
    #pragma unroll
    for (int m = 32; m; m >>= 1) { L += __shfl_xor(L, m); C += __shfl_xor(C, m); }
    __shared__ float rl[4], rc[4];
    if ((tid & 63) == 0) { rl[tid >> 6] = L; rc[tid >> 6] = C; }
    __syncthreads();
    if (tid == 0) {
        out[0] = (rl[0] + rl[1] + rl[2] + rl[3]) * SCALE;
        out[1] = (rc[0] + rc[1] + rc[2] + rc[3]) * SCALE;
    }
}

extern "C" void kernel_launch(void* const* d_in, const int* in_sizes, int n_in,
                              void* d_out, int out_size, void* d_ws, size_t ws_size,
                              hipStream_t stream) {
    const float* mot = (const float*)d_in[0];
    const float* aud = (const float*)d_in[1];
    float* out = (float*)d_out;
    float* ws  = (float*)d_ws;   // 256 blocks x 2 floats, fully overwritten

    lcl_main<<<NBLK, 1024, 0, stream>>>(mot, aud, ws);
    lcl_final<<<1, 256, 0, stream>>>(ws, out);
}

// Round 15
// 21.439 us; speedup vs baseline: 1.0914x; 1.0914x over previous
//
#include <hip/hip_runtime.h>
#include <hip/hip_bf16.h>

typedef __attribute__((ext_vector_type(8))) short bf16x8;
typedef __attribute__((ext_vector_type(4))) float f32x4;

#define T_DIM 4096
#define B_DIM 16
#define D_DIM 128
#define TILE 64          // q rows per tile
#define NTILE 4          // tiles per block (deep pipeline)
#define ROWS 96          // staged rows per tile: t0-16 .. t0+79
#define SROW 136         // bf16 units per row (272 B, 16B-aligned)
#define TBUF (ROWS * SROW)
#define NEGV -1e30f
#define NBLK 256         // 1 block/CU, fully resident
#define SCALE (1.0f / 131072.0f)   // 1 / (B * 2T)

// Barrier that does NOT drain vmcnt (LDS visibility only): prefetch global
// loads stay in flight across it.
#define LDS_BARRIER() asm volatile("s_waitcnt lgkmcnt(0)\n\ts_barrier" ::: "memory")

__global__ __launch_bounds__(512, 2) void lcl_main(
    const float* __restrict__ mot, const float* __restrict__ aud,
    float* __restrict__ ws)
{
    // [buf 0/1][tensor 0=mot,1=aud][ROWS*SROW] -- double-buffered staging
    __shared__ unsigned short sbuf[2 * 2 * TBUF];
    __shared__ float redL[8], redC[8];

    const int tid  = threadIdx.x;
    const int lane = tid & 63;
    const int wv   = tid >> 6;     // 0..7
    const int g32  = tid >> 5;     // 0..15 staging group
    const int l32  = tid & 31;

    // XCD-aware bijective swizzle (256 % 8 == 0): same-XCD blocks are
    // t-adjacent within the same batch -> halo rows hit the same L2.
    const int lin = blockIdx.x;                       // 0..255
    const int swz = (lin & 7) * (NBLK / 8) + (lin >> 3);
    const int by  = swz >> 4;                         // batch 0..15
    const int tg  = swz & 15;                         // t-group (256 t's)
    const int tbase = tg * (NTILE * TILE);
    const size_t base = (size_t)by * (T_DIM * D_DIM);
    const bool edge = (tg == 0) || (tg == 15);        // block-uniform

    // per-wave task: dir = wv>>2, mi = wv&3 (fully self-contained now)
    const int dir = wv >> 2;
    const int mi  = wv & 3;

    const int fr    = lane & 15;
    const int fch   = (lane >> 4) * 8;
    const int col16 = lane & 15;
    const int g     = lane >> 4;

    float4 vm[6], va[6];
    // issue loads for a tile starting at tstart (interior fast path)
    auto issue = [&](int tstart) {
        const size_t off = base + (size_t)(tstart - 16 + g32) * D_DIM + l32 * 4;
        const float* spm = mot + off;
        const float* spa = aud + off;
        if (!edge) {
            #pragma unroll
            for (int i = 0; i < 6; ++i) {
                vm[i] = *reinterpret_cast<const float4*>(spm + (size_t)(16 * i) * D_DIM);
                va[i] = *reinterpret_cast<const float4*>(spa + (size_t)(16 * i) * D_DIM);
            }
        } else {
            #pragma unroll
            for (int i = 0; i < 6; ++i) {
                const bool ok = (unsigned)(tstart - 16 + g32 + 16 * i) < (unsigned)T_DIM;
                vm[i] = make_float4(0.f, 0.f, 0.f, 0.f);
                va[i] = vm[i];
                if (ok) {
                    vm[i] = *reinterpret_cast<const float4*>(spm + (size_t)(16 * i) * D_DIM);
                    va[i] = *reinterpret_cast<const float4*>(spa + (size_t)(16 * i) * D_DIM);
                }
            }
        }
    };

    issue(tbase);                     // prologue: tile-0 loads in registers

    float lossW = 0.f, corrW = 0.f;

    #pragma unroll
    for (int tile = 0; tile < NTILE; ++tile) {
        const int t0  = tbase + tile * TILE;
        const int cur = tile & 1;
        unsigned short* smc = sbuf + (cur * 2 + 0) * TBUF;   // motion buf
        unsigned short* sac = sbuf + (cur * 2 + 1) * TBUF;   // audio buf

        // ---- convert held registers -> bf16 -> LDS (buffer cur) ----
        {
            unsigned short* dpm = smc + g32 * SROW + l32 * 4;
            unsigned short* dpa = sac + g32 * SROW + l32 * 4;
            #pragma unroll
            for (int i = 0; i < 6; ++i) {
                union { __hip_bfloat16 h[4]; uint2 u; } pm, pa;
                pm.h[0] = __float2bfloat16(vm[i].x);
                pm.h[1] = __float2bfloat16(vm[i].y);
                pm.h[2] = __float2bfloat16(vm[i].z);
                pm.h[3] = __float2bfloat16(vm[i].w);
                pa.h[0] = __float2bfloat16(va[i].x);
                pa.h[1] = __float2bfloat16(va[i].y);
                pa.h[2] = __float2bfloat16(va[i].z);
                pa.h[3] = __float2bfloat16(va[i].w);
                *reinterpret_cast<uint2*>(dpm + 16 * i * SROW) = pm.u;
                *reinterpret_cast<uint2*>(dpa + 16 * i * SROW) = pa.u;
            }
        }

        // ---- issue NEXT tile's loads; stay in flight across the barrier ----
        if (tile + 1 < NTILE) issue(t0 + TILE);

        LDS_BARRIER();     // the ONLY barrier per tile: staging of buf cur visible

        // ---- SWAPPED MFMA: A = k rows, B = q rows -> C[row=k_jj][col=q_t]
        // + 4 self-Grams (n0,n1,n2 = k-blocks; nq = q-block) for norms.
        const unsigned short* q = (dir ? sac : smc);
        const unsigned short* k = (dir ? smc : sac);
        f32x4 acc0 = {0.f,0.f,0.f,0.f}, acc1 = acc0, acc2 = acc0;
        f32x4 n0 = acc0, n1 = acc0, n2 = acc0, nq = acc0;
        const unsigned short* qrow = q + (16 * (mi + 1) + fr) * SROW + fch;
        const unsigned short* k0   = k + ((mi + 0) * 16 + fr) * SROW + fch;
        const unsigned short* k1   = k + ((mi + 1) * 16 + fr) * SROW + fch;
        const unsigned short* k2   = k + ((mi + 2) * 16 + fr) * SROW + fch;
        #pragma unroll
        for (int ks = 0; ks < 4; ++ks) {
            bf16x8 bq = *reinterpret_cast<const bf16x8*>(qrow + ks * 32);
            bf16x8 a0 = *reinterpret_cast<const bf16x8*>(k0   + ks * 32);
            bf16x8 a1 = *reinterpret_cast<const bf16x8*>(k1   + ks * 32);
            bf16x8 a2 = *reinterpret_cast<const bf16x8*>(k2   + ks * 32);
            acc0 = __builtin_amdgcn_mfma_f32_16x16x32_bf16(a0, bq, acc0, 0, 0, 0);
            acc1 = __builtin_amdgcn_mfma_f32_16x16x32_bf16(a1, bq, acc1, 0, 0, 0);
            acc2 = __builtin_amdgcn_mfma_f32_16x16x32_bf16(a2, bq, acc2, 0, 0, 0);
            n0   = __builtin_amdgcn_mfma_f32_16x16x32_bf16(a0, a0, n0, 0, 0, 0);
            n1   = __builtin_amdgcn_mfma_f32_16x16x32_bf16(a1, a1, n1, 0, 0, 0);
            n2   = __builtin_amdgcn_mfma_f32_16x16x32_bf16(a2, a2, n2, 0, 0, 0);
            nq   = __builtin_amdgcn_mfma_f32_16x16x32_bf16(bq, bq, nq, 0, 0, 0);
        }

        // ---- in-register norm extraction (no LDS, no barrier) ----
        // Gram diag j lives at lane j+16*(j>>2), reg j&3. Source lanes are
        // 20*g'+r'; every lane pre-selects its would-be diag element.
        const int rs = col16 & 3;
        const float dq = (rs == 0) ? nq[0] : (rs == 1) ? nq[1] : (rs == 2) ? nq[2] : nq[3];
        const float d0 = (rs == 0) ? n0[0] : (rs == 1) ? n0[1] : (rs == 2) ? n0[2] : n0[3];
        const float d1 = (rs == 0) ? n1[0] : (rs == 1) ? n1[1] : (rs == 2) ? n1[2] : n1[3];
        const float d2 = (rs == 0) ? n2[0] : (rs == 1) ? n2[1] : (rs == 2) ? n2[2] : n2[3];
        const float iq = rsqrtf(fmaxf(dq, 1e-24f));
        const float i0 = rsqrtf(fmaxf(d0, 1e-24f));
        const float i1 = rsqrtf(fmaxf(d1, 1e-24f));
        const float i2 = rsqrtf(fmaxf(d2, 1e-24f));

        // broadcasts: invQ for this lane's q-row; sck[bb][r] for its k-rows
        const float scq10 = 10.0f * __shfl(iq, col16 + 16 * (col16 >> 2));
        const int srcn = 20 * g;
        f32x4 sck0, sck1, sck2;
        #pragma unroll
        for (int r = 0; r < 4; ++r) {
            sck0[r] = __shfl(i0, srcn + r);
            sck1[r] = __shfl(i1, srcn + r);
            sck2[r] = __shfl(i2, srcn + r);
        }

        // ---- band reduction: lane owns q-row t=t0+16*mi+col16 ----
        // Single shared max serves both LSEs; loss = log(s/sp).
        const int jbase  = t0 - 16 + 16 * mi + 4 * g;   // + 16b + r = key idx
        const int kkbase = 4 * g - col16;               // + 16b + r = kk

        float lv[12];
        bool  pmk[12];
        float mx = NEGV, mxp = NEGV;
        #pragma unroll
        for (int bb = 0; bb < 3; ++bb) {
            const f32x4 acc = (bb == 0) ? acc0 : ((bb == 1) ? acc1 : acc2);
            const f32x4 sck = (bb == 0) ? sck0 : ((bb == 1) ? sck1 : sck2);
            #pragma unroll
            for (int r = 0; r < 4; ++r) {
                const int kk = kkbase + 16 * bb + r;
                const int jg = jbase  + 16 * bb + r;
                const bool ok = ((unsigned)kk < 32u) && ((unsigned)jg < (unsigned)T_DIM);
                const float li = ok ? acc[r] * (scq10 * sck[r]) : NEGV;
                const bool  pi = ((unsigned)(kk - 12) < 8u);
                lv[bb * 4 + r]  = li;
                pmk[bb * 4 + r] = pi;
                mx  = fmaxf(mx, li);
                mxp = pi ? fmaxf(mxp, li) : mxp;
            }
        }
        mx  = fmaxf(mx,  __shfl_xor(mx,  16));
        mx  = fmaxf(mx,  __shfl_xor(mx,  32));
        mxp = fmaxf(mxp, __shfl_xor(mxp, 16));
        mxp = fmaxf(mxp, __shfl_xor(mxp, 32));

        float s = 0.f, sp = 0.f;
        #pragma unroll
        for (int i = 0; i < 12; ++i) {
            const float e = __expf(lv[i] - mx);   // NEGV entries -> 0
            s  += e;
            sp += pmk[i] ? e : 0.f;
        }
        s  += __shfl_xor(s,  16);  s  += __shfl_xor(s,  32);
        sp += __shfl_xor(sp, 16);  sp += __shfl_xor(sp, 32);

        if (g == 0) {                    // lanes 0..15: one q-row each
            lossW += __logf(s / sp);
            corrW += (mxp >= mx) ? 1.0f : 0.0f;
        }
        // WAR safety without a 2nd barrier: next convert writes buf[tile+1&1],
        // whose last readers (tile-1's MFMA ds_reads) drained at this tile's
        // LDS_BARRIER (lgkmcnt(0)). Reduce phase touches no LDS.
    }

    // ---- block reduction -> per-block partials in ws (no atomics) ----
    #pragma unroll
    for (int m = 32; m; m >>= 1) {
        lossW += __shfl_xor(lossW, m);
        corrW += __shfl_xor(corrW, m);
    }
    if (lane == 0) { redL[wv] = lossW; redC[wv] = corrW; }
    __syncthreads();
    if (tid == 0) {
        float L = 0.f, C = 0.f;
        #pragma unroll
        for (int i = 0; i < 8; ++i) { L += redL[i]; C += redC[i]; }
        ws[2 * swz]     = L;
        ws[2 * swz + 1] = C;
    }
}

__global__ __launch_bounds__(256) void lcl_final(
    const float* __restrict__ ws, float* __restrict__ out)
{
    const int tid = threadIdx.x;
    const float2 v = reinterpret_cast<const float2*>(ws)[tid];   // 256 partials
    float L = v.x, C = v.y;
    #pragma unroll
    for (int m = 32; m; m >>= 1) { L += __shfl_xor(L, m); C += __shfl_xor(C, m); }
    __shared__ float rl[4], rc[4];
    if ((tid & 63) == 0) { rl[tid >> 6] = L; rc[tid >> 6] = C; }
    __syncthreads();
    if (tid == 0) {
        out[0] = (rl[0] + rl[1] + rl[2] + rl[3]) * SCALE;
        out[1] = (rc[0] + rc[1] + rc[2] + rc[3]) * SCALE;
    }
}

extern "C" void kernel_launch(void* const* d_in, const int* in_sizes, int n_in,
                              void* d_out, int out_size, void* d_ws, size_t ws_size,
                              hipStream_t stream) {
    const float* mot = (const float*)d_in[0];
    const float* aud = (const float*)d_in[1];
    float* out = (float*)d_out;
    float* ws  = (float*)d_ws;   // 256 blocks x 2 floats, fully overwritten

    lcl_main<<<NBLK, 512, 0, stream>>>(mot, aud, ws);
    lcl_final<<<1, 256, 0, stream>>>(ws, out);
}